// Round 7
// baseline (179.340 us; speedup 1.0000x reference)
//
#include <hip/hip_runtime.h>

#define NCHUNK 16

typedef __attribute__((ext_vector_type(8))) short bf16x8;
typedef __attribute__((ext_vector_type(4))) float f32x4;

__device__ __forceinline__ unsigned short f2bf(float f){
  union { float f; unsigned u; } v; v.f = f;
  unsigned u = v.u;
  u += 0x7FFFu + ((u >> 16) & 1u);
  return (unsigned short)(u >> 16);
}

__device__ __forceinline__ float bf2f(unsigned short h){
  union { unsigned u; float f; } v; v.u = ((unsigned)h) << 16;
  return v.f;
}

__device__ __forceinline__ void gl_lds16(const void* g, void* l){
  __builtin_amdgcn_global_load_lds((const __attribute__((address_space(1))) unsigned*)g,
                                   (__attribute__((address_space(3))) unsigned*)l, 16, 0, 0);
}

// shared distance expression — identical rounding in both passes
__device__ __forceinline__ float distf(float qx, float qy, float qz, float r1, float4 c){
  float dot = qx*c.x + qy*c.y + qz*c.z;      // mul + fma + fma
  return (r1 + c.w) - 2.0f*dot;              // add + fma(-2)
}

// sorted top-3 insert with indices (round-6 verified)
__device__ __forceinline__ void ins3(float d, int s,
    float& m0, float& m1, float& m2, int& i0, int& i1, int& i2){
  bool c0 = d < m0, c1 = d < m1, c2 = d < m2;
  float om0 = m0, om1 = m1;
  m0 = fminf(om0, d);
  m1 = __builtin_amdgcn_fmed3f(om0, om1, d);
  m2 = __builtin_amdgcn_fmed3f(om1, m2, d);
  int j1 = c0 ? i0 : s;
  int j2 = c1 ? i1 : s;
  i0 = c0 ? s  : i0;
  i1 = c1 ? j1 : i1;
  i2 = c2 ? j2 : i2;
}

// ---- W fp32 -> bf16, plus pack xyz2 candidates (x,y,z,r2)
__global__ __launch_bounds__(256) void k_convert_w(const float* __restrict__ W0, const float* __restrict__ W1,
                            unsigned short* __restrict__ W0b, unsigned short* __restrict__ W1b,
                            const float* __restrict__ xyz2, float* __restrict__ p2p){
  int i = blockIdx.x*256 + threadIdx.x;
  if (i < 256*512) W0b[i] = f2bf(W0[i]);
  if (i < 256*256) W1b[i] = f2bf(W1[i]);
  if (i < 8192){
    int b = i >> 12, s = i & 4095;
    const float* px = xyz2 + (size_t)b*3*4096;
    float x = px[s], y = px[4096+s], z = px[8192+s];
    float4 o; o.x = x; o.y = y; o.z = z; o.w = x*x + y*y + z*z;
    *(float4*)(p2p + (size_t)i*4) = o;
  }
}

// ---- transpose points2 (B,256,S) -> f2t (B,S,256) fp32
__global__ __launch_bounds__(256) void k_tp2(const float* __restrict__ p2, float* __restrict__ f2t){
  __shared__ float tile[64][65];
  int bx = blockIdx.x;      // s/64 (64)
  int by = blockIdx.y;      // c/64 (4)
  int b  = blockIdx.z;
  int t = threadIdx.x; int tx = t & 63; int ty = t >> 6;
  const float* src = p2 + ((size_t)b*256 + by*64)*4096 + bx*64;
  #pragma unroll
  for (int i = 0; i < 16; ++i){
    int c = ty*16 + i;
    tile[c][tx] = src[(size_t)c*4096 + tx];
  }
  __syncthreads();
  float* dst = f2t + ((size_t)b*4096 + (size_t)bx*64)*256 + by*64;
  #pragma unroll
  for (int i = 0; i < 16; ++i){
    int s = ty*16 + i;
    dst[(size_t)s*256 + tx] = tile[tx][s];
  }
}

// ---- transpose points1 (B,256,N) -> Xt (B*N, 512) cols [0,256) bf16
__global__ __launch_bounds__(256) void k_tp1(const float* __restrict__ p1, unsigned short* __restrict__ Xt){
  __shared__ float tile[64][65];
  int bx = blockIdx.x;      // n/64 (256)
  int by = blockIdx.y;      // c/64 (4)
  int b  = blockIdx.z;
  int t = threadIdx.x; int tx = t & 63; int ty = t >> 6;
  const float* src = p1 + ((size_t)b*256 + by*64)*16384 + (size_t)bx*64;
  #pragma unroll
  for (int i = 0; i < 16; ++i){
    int c = ty*16 + i;
    tile[c][tx] = src[(size_t)c*16384 + tx];
  }
  __syncthreads();
  unsigned short* dst = Xt + ((size_t)b*16384 + (size_t)bx*64)*512 + by*64;
  #pragma unroll
  for (int i = 0; i < 16; ++i){
    int n = ty*16 + i;
    dst[(size_t)n*512 + tx] = f2bf(tile[tx][n]);
  }
}

// ---- KNN pass 1: distances only (min/med3 network), per (query, chunk)
__global__ __launch_bounds__(256) void k_knn_d(const float* __restrict__ xyz1, const float* __restrict__ p2p,
                        float* __restrict__ pd){
  int b = blockIdx.z, cc = blockIdx.y;
  int n = blockIdx.x*256 + threadIdx.x;
  const float* q = xyz1 + (size_t)b*3*16384;
  float qx = q[n], qy = q[16384+n], qz = q[32768+n];
  float r1 = qx*qx + qy*qy + qz*qz;
  int s0 = cc*(4096/NCHUNK);
  const float4* cp = (const float4*)p2p + (size_t)b*4096 + s0;
  float m0=3.4e38f, m1=3.4e38f, m2=3.4e38f;
  for (int g = 0; g < (4096/NCHUNK)/8; ++g){
    float4 ca[8];
    #pragma unroll
    for (int u = 0; u < 8; ++u) ca[u] = cp[g*8 + u];
    #pragma unroll
    for (int u = 0; u < 8; ++u){
      float d = distf(qx, qy, qz, r1, ca[u]);
      m2 = __builtin_amdgcn_fmed3f(m1, m2, d);
      m1 = __builtin_amdgcn_fmed3f(m0, m1, d);
      m0 = fminf(m0, d);
    }
  }
  size_t base = (((size_t)b*16384 + n)*NCHUNK + cc)*3;
  pd[base]=m0; pd[base+1]=m1; pd[base+2]=m2;
}

// ---- merge distances: global (d0,d1,d2) per query -> weights + seed threshold
__global__ __launch_bounds__(256) void k_merge_d(const float* __restrict__ pd,
                          float* __restrict__ kw, float* __restrict__ d2g){
  size_t qq = (size_t)blockIdx.x*256 + threadIdx.x;
  float m0=3.4e38f, m1=3.4e38f, m2=3.4e38f;
  size_t base = qq*NCHUNK*3;
  for (int c = 0; c < NCHUNK*3; ++c){
    float d = pd[base+c];
    m2 = __builtin_amdgcn_fmed3f(m1, m2, d);
    m1 = __builtin_amdgcn_fmed3f(m0, m1, d);
    m0 = fminf(m0, d);
  }
  float w0 = 1.0f/(m0+1e-8f), w1 = 1.0f/(m1+1e-8f), w2 = 1.0f/(m2+1e-8f);
  float inv = 1.0f/(w0+w1+w2);
  size_t kb = qq*3;
  kw[kb]=w0*inv; kw[kb+1]=w1*inv; kw[kb+2]=w2*inv;
  d2g[qq] = m2;
}

// ---- KNN pass 2: indices, branch seeded by global d2 (rare: ~4.6%/step)
__global__ __launch_bounds__(256) void k_knn_i(const float* __restrict__ xyz1, const float* __restrict__ p2p,
                        const float* __restrict__ d2g,
                        float* __restrict__ pd, int* __restrict__ pi){
  int b = blockIdx.z, cc = blockIdx.y;
  int n = blockIdx.x*256 + threadIdx.x;
  const float* q = xyz1 + (size_t)b*3*16384;
  float qx = q[n], qy = q[16384+n], qz = q[32768+n];
  float r1 = qx*qx + qy*qy + qz*qz;
  float thr = d2g[(size_t)b*16384 + n];
  int s0 = cc*(4096/NCHUNK);
  const float4* cp = (const float4*)p2p + (size_t)b*4096 + s0;
  float m0=3.4e38f, m1=3.4e38f, m2=3.4e38f;
  int i0=0, i1=0, i2=0;
  for (int g = 0; g < (4096/NCHUNK)/8; ++g){
    float4 ca[8];
    #pragma unroll
    for (int u = 0; u < 8; ++u) ca[u] = cp[g*8 + u];
    #pragma unroll
    for (int u = 0; u < 8; ++u){
      float d = distf(qx, qy, qz, r1, ca[u]);
      // only global-top-3 members (incl. ties) pass; exact insert inside
      if (__builtin_expect((bool)__ballot(d <= thr), 0)){
        ins3(d, s0 + g*8 + u, m0, m1, m2, i0, i1, i2);
      }
    }
  }
  size_t base = (((size_t)b*16384 + n)*NCHUNK + cc)*3;
  pd[base]=m0; pd[base+1]=m1; pd[base+2]=m2;
  pi[base]=i0; pi[base+1]=i1; pi[base+2]=i2;
}

// ---- merge indices (weights already done in k_merge_d)
__global__ __launch_bounds__(256) void k_merge_i(const float* __restrict__ pd, const int* __restrict__ pi,
                          int* __restrict__ ki){
  size_t qq = (size_t)blockIdx.x*256 + threadIdx.x;
  float d0=3.4e38f,d1=3.4e38f,d2=3.4e38f; int i0=0,i1=0,i2=0;
  size_t base = qq*NCHUNK*3;
  for (int c = 0; c < NCHUNK*3; ++c){
    float d = pd[base+c]; int s = pi[base+c];
    if (d < d2){
      if (d < d1){
        d2=d1; i2=i1;
        if (d < d0){ d1=d0; i1=i0; d0=d; i0=s; }
        else       { d1=d; i1=s; }
      } else { d2=d; i2=s; }
    }
  }
  size_t kb = qq*3;
  ki[kb]=i0; ki[kb+1]=i1; ki[kb+2]=i2;
}

// ---- interp -> Xt cols [256,512) bf16
__global__ __launch_bounds__(256) void k_interp(const float* __restrict__ f2t, const int* __restrict__ ki,
                         const float* __restrict__ kw, unsigned short* __restrict__ Xt){
  int t = threadIdx.x;
  int g = t >> 6; int lane = t & 63;
  size_t q = (size_t)blockIdx.x*4 + g;
  int b = (int)(q >> 14);
  const float* f2 = f2t + (size_t)b*4096*256;
  size_t kb = q*3;
  int i0 = ki[kb], i1 = ki[kb+1], i2 = ki[kb+2];
  float w0 = kw[kb], w1 = kw[kb+1], w2 = kw[kb+2];
  const float4 a = *(const float4*)(f2 + (size_t)i0*256 + lane*4);
  const float4 c = *(const float4*)(f2 + (size_t)i1*256 + lane*4);
  const float4 e = *(const float4*)(f2 + (size_t)i2*256 + lane*4);
  ushort4 o;
  o.x = f2bf(w0*a.x + w1*c.x + w2*e.x);
  o.y = f2bf(w0*a.y + w1*c.y + w2*e.y);
  o.z = f2bf(w0*a.z + w1*c.z + w2*e.z);
  o.w = f2bf(w0*a.w + w1*c.w + w2*e.w);
  *(ushort4*)(Xt + q*512 + 256 + lane*4) = o;
}

// ---- NT MFMA GEMM + fused BN-stat partials; bf16 output.
template<int K>
__global__ __launch_bounds__(256) void k_gemm(const unsigned short* __restrict__ A,
                       const unsigned short* __restrict__ Bm,
                       unsigned short* __restrict__ Cb,
                       float* __restrict__ psum, float* __restrict__ psq){
  __shared__ unsigned short As[128*32];
  __shared__ unsigned short Bs[128*32];
  __shared__ float redS[2][128];
  __shared__ float redQ[2][128];
  int t = threadIdx.x;
  int bo = blockIdx.x * 128;
  size_t bn = (size_t)blockIdx.y * 128;
  int w = t >> 6, l = t & 63;
  int wr = w >> 1, wc = w & 1;
  f32x4 acc[4][4] = {};

  const char* Ap = (const char*)A;
  const char* Bp = (const char*)Bm;
  int r0 = t >> 2;
  int cb = (t & 3) * 16;
  for (int k0 = 0; k0 < K; k0 += 32){
    __syncthreads();
    #pragma unroll
    for (int p = 0; p < 2; ++p){
      int off = (t + p*256)*16;
      int r = r0 + p*64;
      gl_lds16(Ap + (size_t)(bo + r)*(K*2) + (size_t)k0*2 + cb, (char*)As + off);
      gl_lds16(Bp + (bn + r)*(K*2) + (size_t)k0*2 + cb, (char*)Bs + off);
    }
    __syncthreads();
    bf16x8 af[4], bfr[4];
    int lr = l & 15, lk = (l >> 4) * 8;
    #pragma unroll
    for (int mt = 0; mt < 4; ++mt)
      af[mt] = *(const bf16x8*)(As + (wr*64 + mt*16 + lr)*32 + lk);
    #pragma unroll
    for (int nt = 0; nt < 4; ++nt)
      bfr[nt] = *(const bf16x8*)(Bs + (wc*64 + nt*16 + lr)*32 + lk);
    #pragma unroll
    for (int mt = 0; mt < 4; ++mt)
      #pragma unroll
      for (int nt = 0; nt < 4; ++nt)
        acc[mt][nt] = __builtin_amdgcn_mfma_f32_16x16x32_bf16(af[mt], bfr[nt], acc[mt][nt], 0, 0, 0);
  }
  int lo = (l >> 4) * 4, ln = l & 15;
  #pragma unroll
  for (int mt = 0; mt < 4; ++mt){
    #pragma unroll
    for (int nt = 0; nt < 4; ++nt){
      size_t n = bn + wc*64 + nt*16 + ln;
      int o = bo + wr*64 + mt*16 + lo;
      ushort4 ov;
      ov.x = f2bf(acc[mt][nt][0]); ov.y = f2bf(acc[mt][nt][1]);
      ov.z = f2bf(acc[mt][nt][2]); ov.w = f2bf(acc[mt][nt][3]);
      *(ushort4*)(Cb + n*256 + o) = ov;
    }
  }
  // BN partials from exact fp32 accumulators
  float ps[16], pq[16];
  #pragma unroll
  for (int mt = 0; mt < 4; ++mt){
    #pragma unroll
    for (int j = 0; j < 4; ++j){
      float s = 0.f, qv = 0.f;
      #pragma unroll
      for (int nt = 0; nt < 4; ++nt){
        float v = acc[mt][nt][j];
        s += v; qv += v*v;
      }
      ps[mt*4+j] = s; pq[mt*4+j] = qv;
    }
  }
  #pragma unroll
  for (int dlt = 1; dlt < 16; dlt <<= 1){
    #pragma unroll
    for (int i = 0; i < 16; ++i){
      ps[i] += __shfl_xor(ps[i], dlt);
      pq[i] += __shfl_xor(pq[i], dlt);
    }
  }
  if ((l & 15) == 0){
    #pragma unroll
    for (int mt = 0; mt < 4; ++mt){
      #pragma unroll
      for (int j = 0; j < 4; ++j){
        int ol = wr*64 + mt*16 + (l>>4)*4 + j;
        redS[wc][ol] = ps[mt*4+j];
        redQ[wc][ol] = pq[mt*4+j];
      }
    }
  }
  __syncthreads();
  if (t < 128){
    psum[(size_t)(bo + t)*256 + blockIdx.y] = redS[0][t] + redS[1][t];
    psq [(size_t)(bo + t)*256 + blockIdx.y] = redQ[0][t] + redQ[1][t];
  }
}

// ---- finalize BN stats: one block per channel, coalesced row
__global__ __launch_bounds__(256) void k_stats_f(const float* __restrict__ psum, const float* __restrict__ psq,
                          const float* __restrict__ gamma, const float* __restrict__ beta,
                          float* __restrict__ scale, float* __restrict__ shift){
  int o = blockIdx.x; int t = threadIdx.x;
  float s = psum[(size_t)o*256 + t];
  float q = psq [(size_t)o*256 + t];
  #pragma unroll
  for (int d = 1; d < 64; d <<= 1){
    s += __shfl_xor(s, d);
    q += __shfl_xor(q, d);
  }
  __shared__ float ls[4], lq[4];
  if ((t & 63) == 0){ ls[t>>6] = s; lq[t>>6] = q; }
  __syncthreads();
  if (t == 0){
    float S = ls[0]+ls[1]+ls[2]+ls[3];
    float Q = lq[0]+lq[1]+lq[2]+lq[3];
    const float invc = 1.0f/32768.0f;
    float mean = S*invc;
    float var = Q*invc - mean*mean;
    float sc = gamma[o]*rsqrtf(var + 1e-5f);
    scale[o] = sc;
    shift[o] = beta[o] - mean*sc;
  }
}

// ---- BN apply + relu: bf16 in -> bf16 out (rows x 256)
__global__ __launch_bounds__(256) void k_apply_y(const unsigned short* __restrict__ Cb, const float* __restrict__ scale,
                          const float* __restrict__ shift, unsigned short* __restrict__ Y){
  size_t i = (size_t)blockIdx.x*256 + threadIdx.x;
  ushort4 v = *(const ushort4*)(Cb + i*4);
  int c = (int)((i*4) & 255);
  ushort4 o;
  o.x = f2bf(fmaxf(0.f, bf2f(v.x)*scale[c]   + shift[c]));
  o.y = f2bf(fmaxf(0.f, bf2f(v.y)*scale[c+1] + shift[c+1]));
  o.z = f2bf(fmaxf(0.f, bf2f(v.z)*scale[c+2] + shift[c+2]));
  o.w = f2bf(fmaxf(0.f, bf2f(v.w)*scale[c+3] + shift[c+3]));
  *(ushort4*)(Y + i*4) = o;
}

// ---- BN apply + relu + transpose: bf16 C2 -> out (B,256,N) fp32
__global__ __launch_bounds__(256) void k_bn_out(const unsigned short* __restrict__ Cb, const float* __restrict__ scale,
                         const float* __restrict__ shift, float* __restrict__ out){
  __shared__ float tile[64][65];
  int bx = blockIdx.x;   // n/64 (256)
  int by = blockIdx.y;   // o/64 (4)
  int b  = blockIdx.z;
  int t = threadIdx.x; int tx = t & 63; int ty = t >> 6;
  const unsigned short* src = Cb + ((size_t)b*16384 + (size_t)bx*64)*256 + by*64;
  int o = by*64 + tx;
  float sc = scale[o], sh = shift[o];
  #pragma unroll
  for (int i = 0; i < 16; ++i){
    int n = ty*16 + i;
    float v = bf2f(src[(size_t)n*256 + tx]);
    tile[n][tx] = fmaxf(0.f, v*sc + sh);
  }
  __syncthreads();
  float* dst = out + ((size_t)b*256 + by*64)*16384 + (size_t)bx*64;
  #pragma unroll
  for (int i = 0; i < 16; ++i){
    int oo = ty*16 + i;
    dst[(size_t)oo*16384 + tx] = tile[tx][oo];
  }
}

extern "C" void kernel_launch(void* const* d_in, const int* in_sizes, int n_in,
                              void* d_out, int out_size, void* d_ws, size_t ws_size,
                              hipStream_t stream){
  const float* xyz1    = (const float*)d_in[0];
  const float* xyz2    = (const float*)d_in[1];
  const float* points1 = (const float*)d_in[2];
  const float* points2 = (const float*)d_in[3];
  const float* W0  = (const float*)d_in[4];
  const float* g0  = (const float*)d_in[6];
  const float* be0 = (const float*)d_in[7];
  const float* W1  = (const float*)d_in[8];
  const float* g1  = (const float*)d_in[10];
  const float* be1 = (const float*)d_in[11];

  char* w = (char*)d_ws;
  size_t o = 0;
  float* f2t = (float*)(w + o); o += 8388608;            // (B,S,256) fp32
  float* p2p = (float*)(w + o); o += 131072;             // packed candidates
  int*   kidx= (int*)(w + o);   o += 393216;             // final idx
  float* kww = (float*)(w + o); o += 393216;             // final weights
  float* d2g = (float*)(w + o); o += 131072;             // global 3rd distance
  unsigned short* W0b = (unsigned short*)(w + o); o += 262144;
  unsigned short* W1b = (unsigned short*)(w + o); o += 131072;
  float* psum = (float*)(w + o); o += 262144;            // [256 o][256 nblk]
  float* psq  = (float*)(w + o); o += 262144;
  float* scale1 = (float*)(w + o); o += 1024;
  float* shift1 = (float*)(w + o); o += 1024;
  float* scale2 = (float*)(w + o); o += 1024;
  float* shift2 = (float*)(w + o); o += 1024;
  float* kpd = (float*)(w + o); o += 6291456;            // per-chunk top3 d
  int*   kpi = (int*)(w + o);   o += 6291456;            // per-chunk top3 idx
  unsigned short* Xt = (unsigned short*)(w + o); size_t xto = o; o += 33554432;  // (32768,512) bf16
  unsigned short* C1b = (unsigned short*)(w + o); o += 16777216;   // (32768,256) bf16
  unsigned short* Yt  = (unsigned short*)(w + o); o += 16777216;   // (32768,256) bf16
  unsigned short* C2b = (unsigned short*)(w + xto);      // reuse Xt region

  k_convert_w<<<512, 256, 0, stream>>>(W0, W1, W0b, W1b, xyz2, p2p);
  k_tp2<<<dim3(64,4,2), 256, 0, stream>>>(points2, f2t);
  k_knn_d<<<dim3(64,NCHUNK,2), 256, 0, stream>>>(xyz1, p2p, kpd);
  k_merge_d<<<128, 256, 0, stream>>>(kpd, kww, d2g);
  k_knn_i<<<dim3(64,NCHUNK,2), 256, 0, stream>>>(xyz1, p2p, d2g, kpd, kpi);
  k_merge_i<<<128, 256, 0, stream>>>(kpd, kpi, kidx);
  k_tp1<<<dim3(256,4,2), 256, 0, stream>>>(points1, Xt);
  k_interp<<<8192, 256, 0, stream>>>(f2t, kidx, kww, Xt);
  k_gemm<512><<<dim3(2,256), 256, 0, stream>>>(W0b, Xt, C1b, psum, psq);
  k_stats_f<<<256, 256, 0, stream>>>(psum, psq, g0, be0, scale1, shift1);
  k_apply_y<<<8192, 256, 0, stream>>>(C1b, scale1, shift1, Yt);
  k_gemm<256><<<dim3(2,256), 256, 0, stream>>>(W1b, Yt, C2b, psum, psq);
  k_stats_f<<<256, 256, 0, stream>>>(psum, psq, g1, be1, scale2, shift2);
  k_bn_out<<<dim3(256,4,2), 256, 0, stream>>>(C2b, scale2, shift2, (float*)d_out);
}

// Round 9
// 159.796 us; speedup vs baseline: 1.1223x; 1.1223x over previous
//
#include <hip/hip_runtime.h>

#define NCHUNK 16

typedef __attribute__((ext_vector_type(8))) short bf16x8;
typedef __attribute__((ext_vector_type(4))) float f32x4;
typedef __attribute__((ext_vector_type(2))) float f32x2;
typedef __attribute__((ext_vector_type(8))) short short8v;

struct PairRec { f32x2 x, y, z, w; };   // 2 candidates: {x0,x1},{y0,y1},{z0,z1},{r2_0,r2_1}

__device__ __forceinline__ unsigned short f2bf(float f){
  union { float f; unsigned u; } v; v.f = f;
  unsigned u = v.u;
  u += 0x7FFFu + ((u >> 16) & 1u);
  return (unsigned short)(u >> 16);
}

__device__ __forceinline__ float bf2f(unsigned short h){
  union { unsigned u; float f; } v; v.u = ((unsigned)h) << 16;
  return v.f;
}

__device__ __forceinline__ void gl_lds16(const void* g, void* l){
  __builtin_amdgcn_global_load_lds((const __attribute__((address_space(1))) unsigned*)g,
                                   (__attribute__((address_space(3))) unsigned*)l, 16, 0, 0);
}

// packed distance, 2 candidates/instr. Per-component op sequence is FORCED to
// mul, fma, fma, add, fma — identical to the scalar pattern of rounds 1-7.
__device__ __forceinline__ f32x2 pkdist(PairRec p, f32x2 qx2, f32x2 qy2, f32x2 qz2, f32x2 r12){
  f32x2 dot = p.x * qx2;                                   // v_pk_mul_f32
  dot = __builtin_elementwise_fma(p.y, qy2, dot);          // v_pk_fma_f32
  dot = __builtin_elementwise_fma(p.z, qz2, dot);          // v_pk_fma_f32
  f32x2 t = r12 + p.w;                                     // v_pk_add_f32
  f32x2 n2 = {-2.0f, -2.0f};
  return __builtin_elementwise_fma(dot, n2, t);            // v_pk_fma_f32
}

// sorted top-3 insert with indices (round-6 verified, exact)
__device__ __forceinline__ void ins3(float d, int s,
    float& m0, float& m1, float& m2, int& i0, int& i1, int& i2){
  bool c0 = d < m0, c1 = d < m1, c2 = d < m2;
  float om0 = m0, om1 = m1;
  m0 = fminf(om0, d);
  m1 = __builtin_amdgcn_fmed3f(om0, om1, d);
  m2 = __builtin_amdgcn_fmed3f(om1, m2, d);
  int j1 = c0 ? i0 : s;
  int j2 = c1 ? i1 : s;
  i0 = c0 ? s  : i0;
  i1 = c1 ? j1 : i1;
  i2 = c2 ? j2 : i2;
}

// ---- W fp32 -> bf16, plus pack xyz2 into pair-records
__global__ __launch_bounds__(256) void k_convert_w(const float* __restrict__ W0, const float* __restrict__ W1,
                            unsigned short* __restrict__ W0b, unsigned short* __restrict__ W1b,
                            const float* __restrict__ xyz2, float* __restrict__ p2pp){
  int i = blockIdx.x*256 + threadIdx.x;
  if (i < 256*512) W0b[i] = f2bf(W0[i]);
  if (i < 256*256) W1b[i] = f2bf(W1[i]);
  if (i < 8192){
    int b = i >> 12, s = i & 4095;
    const float* px = xyz2 + (size_t)b*3*4096;
    float x = px[s], y = px[4096+s], z = px[8192+s];
    float r2 = x*x + y*y + z*z;
    size_t base = (size_t)b*16384 + (size_t)(s >> 1)*8 + (s & 1);
    p2pp[base+0] = x; p2pp[base+2] = y; p2pp[base+4] = z; p2pp[base+6] = r2;
  }
}

// ---- transpose points2 (B,256,S) -> f2t (B,S,256) fp32
__global__ __launch_bounds__(256) void k_tp2(const float* __restrict__ p2, float* __restrict__ f2t){
  __shared__ float tile[64][65];
  int bx = blockIdx.x;      // s/64 (64)
  int by = blockIdx.y;      // c/64 (4)
  int b  = blockIdx.z;
  int t = threadIdx.x; int tx = t & 63; int ty = t >> 6;
  const float* src = p2 + ((size_t)b*256 + by*64)*4096 + bx*64;
  #pragma unroll
  for (int i = 0; i < 16; ++i){
    int c = ty*16 + i;
    tile[c][tx] = src[(size_t)c*4096 + tx];
  }
  __syncthreads();
  float* dst = f2t + ((size_t)b*4096 + (size_t)bx*64)*256 + by*64;
  #pragma unroll
  for (int i = 0; i < 16; ++i){
    int s = ty*16 + i;
    dst[(size_t)s*256 + tx] = tile[tx][s];
  }
}

// ---- transpose points1 (B,256,N) -> Xt (B*N, 512) cols [0,256) bf16
__global__ __launch_bounds__(256) void k_tp1(const float* __restrict__ p1, unsigned short* __restrict__ Xt){
  __shared__ float tile[64][65];
  int bx = blockIdx.x;      // n/64 (256)
  int by = blockIdx.y;      // c/64 (4)
  int b  = blockIdx.z;
  int t = threadIdx.x; int tx = t & 63; int ty = t >> 6;
  const float* src = p1 + ((size_t)b*256 + by*64)*16384 + (size_t)bx*64;
  #pragma unroll
  for (int i = 0; i < 16; ++i){
    int c = ty*16 + i;
    tile[c][tx] = src[(size_t)c*16384 + tx];
  }
  __syncthreads();
  unsigned short* dst = Xt + ((size_t)b*16384 + (size_t)bx*64)*512 + by*64;
  #pragma unroll
  for (int i = 0; i < 16; ++i){
    int n = ty*16 + i;
    dst[(size_t)n*512 + tx] = f2bf(tile[tx][n]);
  }
}

// ---- KNN: single pass, packed-pair distances + exact ins3
__global__ __launch_bounds__(256) void k_knn(const float* __restrict__ xyz1, const float* __restrict__ p2pp,
                      float* __restrict__ pd, int* __restrict__ pi){
  int b = blockIdx.z, cc = blockIdx.y;
  int n = blockIdx.x*256 + threadIdx.x;
  const float* q = xyz1 + (size_t)b*3*16384;
  float qx = q[n], qy = q[16384+n], qz = q[32768+n];
  float r1 = qx*qx + qy*qy + qz*qz;
  f32x2 qx2 = {qx,qx}, qy2 = {qy,qy}, qz2 = {qz,qz}, r12 = {r1,r1};
  const int NP = (4096/NCHUNK)/2;        // pairs per chunk = 128
  int s0 = cc*(4096/NCHUNK);
  const PairRec* pp = (const PairRec*)p2pp + (size_t)b*2048 + cc*NP;
  float m0=3.4e38f, m1=3.4e38f, m2=3.4e38f;
  int i0=0, i1=0, i2=0;
  for (int g = 0; g < NP/4; ++g){
    PairRec pA = pp[g*4+0], pB = pp[g*4+1], pC = pp[g*4+2], pD = pp[g*4+3];
    int sb = s0 + g*8;
    f32x2 dA = pkdist(pA, qx2, qy2, qz2, r12);
    ins3(dA.x, sb+0, m0,m1,m2, i0,i1,i2);
    ins3(dA.y, sb+1, m0,m1,m2, i0,i1,i2);
    f32x2 dB = pkdist(pB, qx2, qy2, qz2, r12);
    ins3(dB.x, sb+2, m0,m1,m2, i0,i1,i2);
    ins3(dB.y, sb+3, m0,m1,m2, i0,i1,i2);
    f32x2 dC = pkdist(pC, qx2, qy2, qz2, r12);
    ins3(dC.x, sb+4, m0,m1,m2, i0,i1,i2);
    ins3(dC.y, sb+5, m0,m1,m2, i0,i1,i2);
    f32x2 dD = pkdist(pD, qx2, qy2, qz2, r12);
    ins3(dD.x, sb+6, m0,m1,m2, i0,i1,i2);
    ins3(dD.y, sb+7, m0,m1,m2, i0,i1,i2);
  }
  size_t base = (((size_t)b*16384 + n)*NCHUNK + cc)*3;
  pd[base]=m0; pd[base+1]=m1; pd[base+2]=m2;
  pi[base]=i0; pi[base+1]=i1; pi[base+2]=i2;
}

__global__ __launch_bounds__(256) void k_knn_merge(const float* __restrict__ pd, const int* __restrict__ pi,
                            int* __restrict__ ki, float* __restrict__ kw){
  size_t qq = (size_t)blockIdx.x*256 + threadIdx.x;
  float d0=3.4e38f,d1=3.4e38f,d2=3.4e38f; int i0=0,i1=0,i2=0;
  size_t base = qq*NCHUNK*3;
  for (int c = 0; c < NCHUNK*3; ++c){
    float d = pd[base+c]; int s = pi[base+c];
    if (d < d2){
      if (d < d1){
        d2=d1; i2=i1;
        if (d < d0){ d1=d0; i1=i0; d0=d; i0=s; }
        else       { d1=d; i1=s; }
      } else { d2=d; i2=s; }
    }
  }
  float w0 = 1.0f/(d0+1e-8f), w1 = 1.0f/(d1+1e-8f), w2 = 1.0f/(d2+1e-8f);
  float inv = 1.0f/(w0+w1+w2);
  size_t kb = qq*3;
  ki[kb]=i0; ki[kb+1]=i1; ki[kb+2]=i2;
  kw[kb]=w0*inv; kw[kb+1]=w1*inv; kw[kb+2]=w2*inv;
}

// ---- interp -> Xt cols [256,512) bf16
__global__ __launch_bounds__(256) void k_interp(const float* __restrict__ f2t, const int* __restrict__ ki,
                         const float* __restrict__ kw, unsigned short* __restrict__ Xt){
  int t = threadIdx.x;
  int g = t >> 6; int lane = t & 63;
  size_t q = (size_t)blockIdx.x*4 + g;
  int b = (int)(q >> 14);
  const float* f2 = f2t + (size_t)b*4096*256;
  size_t kb = q*3;
  int i0 = ki[kb], i1 = ki[kb+1], i2 = ki[kb+2];
  float w0 = kw[kb], w1 = kw[kb+1], w2 = kw[kb+2];
  const float4 a = *(const float4*)(f2 + (size_t)i0*256 + lane*4);
  const float4 c = *(const float4*)(f2 + (size_t)i1*256 + lane*4);
  const float4 e = *(const float4*)(f2 + (size_t)i2*256 + lane*4);
  ushort4 o;
  o.x = f2bf(w0*a.x + w1*c.x + w2*e.x);
  o.y = f2bf(w0*a.y + w1*c.y + w2*e.y);
  o.z = f2bf(w0*a.z + w1*c.z + w2*e.z);
  o.w = f2bf(w0*a.w + w1*c.w + w2*e.w);
  *(ushort4*)(Xt + q*512 + 256 + lane*4) = o;
}

// ---- NT MFMA GEMM + fused BN-stat partials; bf16 output (gemm1)
template<int K>
__global__ __launch_bounds__(256) void k_gemm(const unsigned short* __restrict__ A,
                       const unsigned short* __restrict__ Bm,
                       unsigned short* __restrict__ Cb,
                       float* __restrict__ psum, float* __restrict__ psq){
  __shared__ unsigned short As[128*32];
  __shared__ unsigned short Bs[128*32];
  __shared__ float redS[2][128];
  __shared__ float redQ[2][128];
  int t = threadIdx.x;
  int bo = blockIdx.x * 128;
  size_t bn = (size_t)blockIdx.y * 128;
  int w = t >> 6, l = t & 63;
  int wr = w >> 1, wc = w & 1;
  f32x4 acc[4][4] = {};

  const char* Ap = (const char*)A;
  const char* Bp = (const char*)Bm;
  int r0 = t >> 2;
  int cb = (t & 3) * 16;
  for (int k0 = 0; k0 < K; k0 += 32){
    __syncthreads();
    #pragma unroll
    for (int p = 0; p < 2; ++p){
      int off = (t + p*256)*16;
      int r = r0 + p*64;
      gl_lds16(Ap + (size_t)(bo + r)*(K*2) + (size_t)k0*2 + cb, (char*)As + off);
      gl_lds16(Bp + (bn + r)*(K*2) + (size_t)k0*2 + cb, (char*)Bs + off);
    }
    __syncthreads();
    bf16x8 af[4], bfr[4];
    int lr = l & 15, lk = (l >> 4) * 8;
    #pragma unroll
    for (int mt = 0; mt < 4; ++mt)
      af[mt] = *(const bf16x8*)(As + (wr*64 + mt*16 + lr)*32 + lk);
    #pragma unroll
    for (int nt = 0; nt < 4; ++nt)
      bfr[nt] = *(const bf16x8*)(Bs + (wc*64 + nt*16 + lr)*32 + lk);
    #pragma unroll
    for (int mt = 0; mt < 4; ++mt)
      #pragma unroll
      for (int nt = 0; nt < 4; ++nt)
        acc[mt][nt] = __builtin_amdgcn_mfma_f32_16x16x32_bf16(af[mt], bfr[nt], acc[mt][nt], 0, 0, 0);
  }
  int lo = (l >> 4) * 4, ln = l & 15;
  #pragma unroll
  for (int mt = 0; mt < 4; ++mt){
    #pragma unroll
    for (int nt = 0; nt < 4; ++nt){
      size_t n = bn + wc*64 + nt*16 + ln;
      int o = bo + wr*64 + mt*16 + lo;
      ushort4 ov;
      ov.x = f2bf(acc[mt][nt][0]); ov.y = f2bf(acc[mt][nt][1]);
      ov.z = f2bf(acc[mt][nt][2]); ov.w = f2bf(acc[mt][nt][3]);
      *(ushort4*)(Cb + n*256 + o) = ov;
    }
  }
  float ps[16], pq[16];
  #pragma unroll
  for (int mt = 0; mt < 4; ++mt){
    #pragma unroll
    for (int j = 0; j < 4; ++j){
      float s = 0.f, qv = 0.f;
      #pragma unroll
      for (int nt = 0; nt < 4; ++nt){
        float v = acc[mt][nt][j];
        s += v; qv += v*v;
      }
      ps[mt*4+j] = s; pq[mt*4+j] = qv;
    }
  }
  #pragma unroll
  for (int dlt = 1; dlt < 16; dlt <<= 1){
    #pragma unroll
    for (int i = 0; i < 16; ++i){
      ps[i] += __shfl_xor(ps[i], dlt);
      pq[i] += __shfl_xor(pq[i], dlt);
    }
  }
  if ((l & 15) == 0){
    #pragma unroll
    for (int mt = 0; mt < 4; ++mt){
      #pragma unroll
      for (int j = 0; j < 4; ++j){
        int ol = wr*64 + mt*16 + (l>>4)*4 + j;
        redS[wc][ol] = ps[mt*4+j];
        redQ[wc][ol] = pq[mt*4+j];
      }
    }
  }
  __syncthreads();
  if (t < 128){
    psum[(size_t)(bo + t)*256 + blockIdx.y] = redS[0][t] + redS[1][t];
    psq [(size_t)(bo + t)*256 + blockIdx.y] = redQ[0][t] + redQ[1][t];
  }
}

// ---- gemm2 with fused BN-apply+ReLU on the B operand (replaces apply_y):
//      B[n][c] = relu(bf2f(C1[n][c])*scale[c]+shift[c]) staged reg->LDS as bf16
__global__ __launch_bounds__(256) void k_gemm2(const unsigned short* __restrict__ A,
                       const unsigned short* __restrict__ C1,
                       const float* __restrict__ scale, const float* __restrict__ shift,
                       unsigned short* __restrict__ Cb,
                       float* __restrict__ psum, float* __restrict__ psq){
  const int K = 256;
  __shared__ unsigned short As[128*32];
  __shared__ unsigned short Bs[128*32];
  __shared__ float redS[2][128];
  __shared__ float redQ[2][128];
  int t = threadIdx.x;
  int bo = blockIdx.x * 128;
  size_t bn = (size_t)blockIdx.y * 128;
  int w = t >> 6, l = t & 63;
  int wr = w >> 1, wc = w & 1;
  f32x4 acc[4][4] = {};

  const char* Ap = (const char*)A;
  int r0 = t >> 2;
  int cb = (t & 3) * 16;
  int ce0 = (t & 3) * 8;
  for (int k0 = 0; k0 < K; k0 += 32){
    int ce = k0 + ce0;
    float4 a0 = *(const float4*)(scale+ce); float4 a1 = *(const float4*)(scale+ce+4);
    float4 b0 = *(const float4*)(shift+ce); float4 b1 = *(const float4*)(shift+ce+4);
    float sc[8] = {a0.x,a0.y,a0.z,a0.w,a1.x,a1.y,a1.z,a1.w};
    float sh[8] = {b0.x,b0.y,b0.z,b0.w,b1.x,b1.y,b1.z,b1.w};
    short8v vin[2];
    #pragma unroll
    for (int p = 0; p < 2; ++p){
      int r = r0 + p*64;
      vin[p] = *(const short8v*)(C1 + (bn + r)*256 + ce);
    }
    __syncthreads();
    #pragma unroll
    for (int p = 0; p < 2; ++p){
      int r = r0 + p*64;
      gl_lds16(Ap + (size_t)(bo + r)*(K*2) + (size_t)k0*2 + cb, (char*)As + (t + p*256)*16);
    }
    #pragma unroll
    for (int p = 0; p < 2; ++p){
      short8v pv;
      #pragma unroll
      for (int j = 0; j < 8; ++j){
        float y = fmaxf(0.f, bf2f((unsigned short)vin[p][j])*sc[j] + sh[j]);
        pv[j] = (short)f2bf(y);
      }
      *(short8v*)((char*)Bs + (t + p*256)*16) = pv;
    }
    __syncthreads();
    bf16x8 af[4], bfr[4];
    int lr = l & 15, lk = (l >> 4) * 8;
    #pragma unroll
    for (int mt = 0; mt < 4; ++mt)
      af[mt] = *(const bf16x8*)(As + (wr*64 + mt*16 + lr)*32 + lk);
    #pragma unroll
    for (int nt = 0; nt < 4; ++nt)
      bfr[nt] = *(const bf16x8*)(Bs + (wc*64 + nt*16 + lr)*32 + lk);
    #pragma unroll
    for (int mt = 0; mt < 4; ++mt)
      #pragma unroll
      for (int nt = 0; nt < 4; ++nt)
        acc[mt][nt] = __builtin_amdgcn_mfma_f32_16x16x32_bf16(af[mt], bfr[nt], acc[mt][nt], 0, 0, 0);
  }
  int lo = (l >> 4) * 4, ln = l & 15;
  #pragma unroll
  for (int mt = 0; mt < 4; ++mt){
    #pragma unroll
    for (int nt = 0; nt < 4; ++nt){
      size_t n = bn + wc*64 + nt*16 + ln;
      int o = bo + wr*64 + mt*16 + lo;
      ushort4 ov;
      ov.x = f2bf(acc[mt][nt][0]); ov.y = f2bf(acc[mt][nt][1]);
      ov.z = f2bf(acc[mt][nt][2]); ov.w = f2bf(acc[mt][nt][3]);
      *(ushort4*)(Cb + n*256 + o) = ov;
    }
  }
  float ps[16], pq[16];
  #pragma unroll
  for (int mt = 0; mt < 4; ++mt){
    #pragma unroll
    for (int j = 0; j < 4; ++j){
      float s = 0.f, qv = 0.f;
      #pragma unroll
      for (int nt = 0; nt < 4; ++nt){
        float v = acc[mt][nt][j];
        s += v; qv += v*v;
      }
      ps[mt*4+j] = s; pq[mt*4+j] = qv;
    }
  }
  #pragma unroll
  for (int dlt = 1; dlt < 16; dlt <<= 1){
    #pragma unroll
    for (int i = 0; i < 16; ++i){
      ps[i] += __shfl_xor(ps[i], dlt);
      pq[i] += __shfl_xor(pq[i], dlt);
    }
  }
  if ((l & 15) == 0){
    #pragma unroll
    for (int mt = 0; mt < 4; ++mt){
      #pragma unroll
      for (int j = 0; j < 4; ++j){
        int ol = wr*64 + mt*16 + (l>>4)*4 + j;
        redS[wc][ol] = ps[mt*4+j];
        redQ[wc][ol] = pq[mt*4+j];
      }
    }
  }
  __syncthreads();
  if (t < 128){
    psum[(size_t)(bo + t)*256 + blockIdx.y] = redS[0][t] + redS[1][t];
    psq [(size_t)(bo + t)*256 + blockIdx.y] = redQ[0][t] + redQ[1][t];
  }
}

// ---- finalize BN stats: one block per channel, coalesced row
__global__ __launch_bounds__(256) void k_stats_f(const float* __restrict__ psum, const float* __restrict__ psq,
                          const float* __restrict__ gamma, const float* __restrict__ beta,
                          float* __restrict__ scale, float* __restrict__ shift){
  int o = blockIdx.x; int t = threadIdx.x;
  float s = psum[(size_t)o*256 + t];
  float q = psq [(size_t)o*256 + t];
  #pragma unroll
  for (int d = 1; d < 64; d <<= 1){
    s += __shfl_xor(s, d);
    q += __shfl_xor(q, d);
  }
  __shared__ float ls[4], lq[4];
  if ((t & 63) == 0){ ls[t>>6] = s; lq[t>>6] = q; }
  __syncthreads();
  if (t == 0){
    float S = ls[0]+ls[1]+ls[2]+ls[3];
    float Q = lq[0]+lq[1]+lq[2]+lq[3];
    const float invc = 1.0f/32768.0f;
    float mean = S*invc;
    float var = Q*invc - mean*mean;
    float sc = gamma[o]*rsqrtf(var + 1e-5f);
    scale[o] = sc;
    shift[o] = beta[o] - mean*sc;
  }
}

// ---- BN apply + relu + transpose: bf16 C2 -> out (B,256,N) fp32
__global__ __launch_bounds__(256) void k_bn_out(const unsigned short* __restrict__ Cb, const float* __restrict__ scale,
                         const float* __restrict__ shift, float* __restrict__ out){
  __shared__ float tile[64][65];
  int bx = blockIdx.x;   // n/64 (256)
  int by = blockIdx.y;   // o/64 (4)
  int b  = blockIdx.z;
  int t = threadIdx.x; int tx = t & 63; int ty = t >> 6;
  const unsigned short* src = Cb + ((size_t)b*16384 + (size_t)bx*64)*256 + by*64;
  int o = by*64 + tx;
  float sc = scale[o], sh = shift[o];
  #pragma unroll
  for (int i = 0; i < 16; ++i){
    int n = ty*16 + i;
    float v = bf2f(src[(size_t)n*256 + tx]);
    tile[n][tx] = fmaxf(0.f, v*sc + sh);
  }
  __syncthreads();
  float* dst = out + ((size_t)b*256 + by*64)*16384 + (size_t)bx*64;
  #pragma unroll
  for (int i = 0; i < 16; ++i){
    int oo = ty*16 + i;
    dst[(size_t)oo*16384 + tx] = tile[tx][oo];
  }
}

extern "C" void kernel_launch(void* const* d_in, const int* in_sizes, int n_in,
                              void* d_out, int out_size, void* d_ws, size_t ws_size,
                              hipStream_t stream){
  const float* xyz1    = (const float*)d_in[0];
  const float* xyz2    = (const float*)d_in[1];
  const float* points1 = (const float*)d_in[2];
  const float* points2 = (const float*)d_in[3];
  const float* W0  = (const float*)d_in[4];
  const float* g0  = (const float*)d_in[6];
  const float* be0 = (const float*)d_in[7];
  const float* W1  = (const float*)d_in[8];
  const float* g1  = (const float*)d_in[10];
  const float* be1 = (const float*)d_in[11];

  char* w = (char*)d_ws;
  size_t o = 0;
  float* f2t = (float*)(w + o); o += 8388608;            // (B,S,256) fp32
  float* p2pp= (float*)(w + o); o += 131072;             // packed pair-records
  int*   kidx= (int*)(w + o);   o += 393216;             // final idx
  float* kww = (float*)(w + o); o += 393216;             // final weights
  unsigned short* W0b = (unsigned short*)(w + o); o += 262144;
  unsigned short* W1b = (unsigned short*)(w + o); o += 131072;
  float* psum = (float*)(w + o); o += 262144;            // [256 o][256 nblk]
  float* psq  = (float*)(w + o); o += 262144;
  float* scale1 = (float*)(w + o); o += 1024;
  float* shift1 = (float*)(w + o); o += 1024;
  float* scale2 = (float*)(w + o); o += 1024;
  float* shift2 = (float*)(w + o); o += 1024;
  float* kpd = (float*)(w + o); o += 6291456;            // per-chunk top3 d
  int*   kpi = (int*)(w + o);   o += 6291456;            // per-chunk top3 idx
  unsigned short* Xt = (unsigned short*)(w + o); size_t xto = o; o += 33554432;  // (32768,512) bf16
  unsigned short* C1b = (unsigned short*)(w + o); o += 16777216;   // (32768,256) bf16
  unsigned short* C2b = (unsigned short*)(w + xto);      // reuse Xt region

  k_convert_w<<<512, 256, 0, stream>>>(W0, W1, W0b, W1b, xyz2, p2pp);
  k_tp2<<<dim3(64,4,2), 256, 0, stream>>>(points2, f2t);
  k_knn<<<dim3(64,NCHUNK,2), 256, 0, stream>>>(xyz1, p2pp, kpd, kpi);
  k_knn_merge<<<128, 256, 0, stream>>>(kpd, kpi, kidx, kww);
  k_tp1<<<dim3(256,4,2), 256, 0, stream>>>(points1, Xt);
  k_interp<<<8192, 256, 0, stream>>>(f2t, kidx, kww, Xt);
  k_gemm<512><<<dim3(2,256), 256, 0, stream>>>(W0b, Xt, C1b, psum, psq);
  k_stats_f<<<256, 256, 0, stream>>>(psum, psq, g0, be0, scale1, shift1);
  k_gemm2<<<dim3(2,256), 256, 0, stream>>>(W1b, C1b, scale1, shift1, C2b, psum, psq);
  k_stats_f<<<256, 256, 0, stream>>>(psum, psq, g1, be1, scale2, shift2);
  k_bn_out<<<dim3(256,4,2), 256, 0, stream>>>(C2b, scale2, shift2, (float*)d_out);
}